// Round 7
// baseline (3445.235 us; speedup 1.0000x reference)
//
#include <hip/hip_runtime.h>

typedef short bf16x8 __attribute__((ext_vector_type(8)));
typedef float f32x4 __attribute__((ext_vector_type(4)));
typedef unsigned int u32x4 __attribute__((ext_vector_type(4)));
typedef unsigned long long u64x2 __attribute__((ext_vector_type(2)));

__device__ __forceinline__ unsigned short f2bf(float f) {
  unsigned u = __float_as_uint(f);
  unsigned r = (u + 0x7FFFu + ((u >> 16) & 1u)) >> 16;
  return (unsigned short)r;
}
__device__ __forceinline__ float bf2f(unsigned short s) {
  return __uint_as_float(((unsigned)s) << 16);
}
__device__ __forceinline__ float sigm(float x) {
  return __builtin_amdgcn_rcpf(1.f + __expf(-x));
}
__device__ __forceinline__ float tanh_a(float x) {
  return 1.f - 2.f * __builtin_amdgcn_rcpf(__expf(2.f * x) + 1.f);
}

__device__ __forceinline__ void gload_lds16(const void* g, void* l) {
  __builtin_amdgcn_global_load_lds(
      (const __attribute__((address_space(1))) unsigned int*)g,
      (__attribute__((address_space(3))) unsigned int*)l, 16, 0, 0);
}

#define ALOAD(p)     __hip_atomic_load((p), __ATOMIC_RELAXED, __HIP_MEMORY_SCOPE_AGENT)
#define ASTORE(p, v) __hip_atomic_store((p), (v), __ATOMIC_RELAXED, __HIP_MEMORY_SCOPE_AGENT)

// ---------------- pack kernels ----------------

__global__ void k_cvt_x(const float* __restrict__ x, unsigned short* __restrict__ xb, int n4) {
  int i = blockIdx.x * blockDim.x + threadIdx.x;
  if (i < n4) {
    float4 v = ((const float4*)x)[i];
    ushort4 o;
    o.x = f2bf(v.x); o.y = f2bf(v.y); o.z = f2bf(v.z); o.w = f2bf(v.w);
    ((ushort4*)xb)[i] = o;
  }
}

__global__ void k_pack_w(const float* __restrict__ wxi, const float* __restrict__ wxf,
                         const float* __restrict__ wxg, const float* __restrict__ wxo,
                         const float* __restrict__ whi, const float* __restrict__ whf,
                         const float* __restrict__ whg, const float* __restrict__ who,
                         unsigned short* __restrict__ wxt, unsigned short* __restrict__ whp) {
  const float* srcs[8] = {wxi, wxf, wxg, wxo, whi, whf, whg, who};
  int slab = blockIdx.z;
  const float* src = srcs[slab];
  int gate = slab & 3;
  bool is_wh = slab >= 4;
  __shared__ float tile[32][33];
  int tx = threadIdx.x, ty = threadIdx.y;
  int j0 = blockIdx.x * 32, k0 = blockIdx.y * 32;
  #pragma unroll
  for (int i = 0; i < 32; i += 8)
    tile[ty + i][tx] = src[(size_t)(k0 + ty + i) * 1024 + j0 + tx];
  __syncthreads();
  unsigned short* dst = is_wh ? whp : wxt;
  #pragma unroll
  for (int i = 0; i < 32; i += 8) {
    int j = j0 + ty + i;
    int k = k0 + tx;
    float v = tile[tx][ty + i];
    int row = is_wh ? ((j >> 2) * 16 + gate * 4 + (j & 3)) : (gate * 1024 + j);
    dst[(size_t)row * 1024 + k] = f2bf(v);
  }
}

__global__ void k_bias(const float* bxi, const float* bhi, const float* bxf, const float* bhf,
                       const float* bxg, const float* bhg, const float* bxo, const float* bho,
                       float* __restrict__ bx4) {
  int n = blockIdx.x * 256 + threadIdx.x;  // 0..4095
  int gate = n >> 10, j = n & 1023;
  const float* a = gate == 0 ? bxi : gate == 1 ? bxf : gate == 2 ? bxg : bxo;
  const float* b = gate == 0 ? bhi : gate == 1 ? bhf : gate == 2 ? bhg : bho;
  bx4[n] = a[j] + b[j];
}

// init tagged h buffer (tag 0 == valid h(0)=0) through the agent-atomic path.
__global__ void k_init(unsigned long long* __restrict__ hb) {
  int i = blockIdx.x * 256 + threadIdx.x;  // 0..65535 -> 512 KiB
  ASTORE(hb + i, 0ull);
}

// ---------------- xproj GEMM: (32768x1024) @ (1024x4096) -> bf16 [t][b][pc] ----------------
// output column order = packed-wh order: pc = (j>>2)*16 + gate*4 + (j&3)

__global__ __launch_bounds__(256) void k_xproj(
    const unsigned short* __restrict__ xb,   // [32768][1024] bf16
    const unsigned short* __restrict__ wxt,  // [4096][1024]  bf16 (B^T)
    const float* __restrict__ bx4,           // [4096]
    unsigned short* __restrict__ xp)         // [512][64][4096] bf16, permuted cols
{
  __shared__ __align__(16) short As[128 * 64];
  __shared__ __align__(16) short Bs[128 * 64];
  const int tid = threadIdx.x;
  const int bid = blockIdx.x;
  const int m0 = (bid >> 5) * 128;
  const int n0 = (bid & 31) * 128;
  const int lane = tid & 63, w = tid >> 6;
  const int l15 = lane & 15, hi = lane >> 4;
  const int mrow0 = (w >> 1) * 64, ncol0 = (w & 1) * 64;

  f32x4 acc[4][4] = {};
  const char* xbB = (const char*)xb;
  const char* wtB = (const char*)wxt;

  for (int ks = 0; ks < 16; ++ks) {
    #pragma unroll
    for (int c = 0; c < 4; ++c) {
      int d = c * 4096 + tid * 16;
      int r = d >> 7;
      int kb = (d & 127) ^ ((r & 7) << 4);
      gload_lds16(xbB + ((size_t)(m0 + r) * 2048 + ks * 128 + kb), (char*)As + d);
    }
    #pragma unroll
    for (int c = 0; c < 4; ++c) {
      int d = c * 4096 + tid * 16;
      int r = d >> 7;
      int kb = (d & 127) ^ ((r & 7) << 4);
      gload_lds16(wtB + ((size_t)(n0 + r) * 2048 + ks * 128 + kb), (char*)Bs + d);
    }
    __syncthreads();
    #pragma unroll
    for (int kk = 0; kk < 2; ++kk) {
      bf16x8 a[4], b[4];
      #pragma unroll
      for (int mt = 0; mt < 4; ++mt) {
        int r = mrow0 + mt * 16 + l15;
        int byt = r * 128 + ((kk * 64 + hi * 16) ^ ((r & 7) << 4));
        a[mt] = *(const bf16x8*)((const char*)As + byt);
      }
      #pragma unroll
      for (int nt = 0; nt < 4; ++nt) {
        int r = ncol0 + nt * 16 + l15;
        int byt = r * 128 + ((kk * 64 + hi * 16) ^ ((r & 7) << 4));
        b[nt] = *(const bf16x8*)((const char*)Bs + byt);
      }
      #pragma unroll
      for (int mt = 0; mt < 4; ++mt)
        #pragma unroll
        for (int nt = 0; nt < 4; ++nt)
          acc[mt][nt] = __builtin_amdgcn_mfma_f32_16x16x32_bf16(a[mt], b[nt], acc[mt][nt], 0, 0, 0);
    }
    __syncthreads();
  }
  float bias[4];
  int pcol[4];
  #pragma unroll
  for (int nt = 0; nt < 4; ++nt) {
    int n = n0 + ncol0 + nt * 16 + l15;
    bias[nt] = bx4[n];
    int gate = n >> 10, j = n & 1023;
    pcol[nt] = (j >> 2) * 16 + gate * 4 + (j & 3);
  }
  #pragma unroll
  for (int mt = 0; mt < 4; ++mt)
    #pragma unroll
    for (int nt = 0; nt < 4; ++nt) {
      #pragma unroll
      for (int ri = 0; ri < 4; ++ri) {
        int row = m0 + mrow0 + mt * 16 + hi * 4 + ri;       // m = b*512 + t
        int prow = (row & 511) * 64 + (row >> 9);           // -> t*64 + b
        xp[(size_t)prow * 4096 + pcol[nt]] = f2bf(acc[mt][nt][ri] + bias[nt]);
      }
    }
}

// ---------------- persistent recurrence: tag-embedded h exchange, barrier-free ----------------
// 4 groups x 32 blocks x 512 threads. Group q owns batch rows [16q,16q+16).
// Block (q,cg) owns h-cols [32cg,32cg+32); wave w owns cols [32cg+4w,+4) x 4 gates.
// h stored as dword = bf16val | (step<<16); consumers poll their stage loads directly.
// wh is FORCED register-resident (asm pin). One __syncthreads per step, no flags.

__global__ __launch_bounds__(512, 2) void k_lstm(
    const unsigned short* __restrict__ whp,  // [4096][1024] bf16 packed
    const unsigned short* __restrict__ xp,   // [512][64][4096] bf16 permuted (biases folded)
    unsigned int* __restrict__ hb2,          // [2][64][1024] tagged dwords (zeroed by k_init)
    float* __restrict__ out)                 // h (65536) then c (65536), fp32
{
  const int bid = blockIdx.x;
  const int q = bid >> 5;         // batch group (0..3)
  const int cg = bid & 31;        // column group (0..31)
  const int r0 = q * 16;
  const int tid = threadIdx.x;
  const int lane = tid & 63, w = tid >> 6;     // 8 waves
  const int l15 = lane & 15, hi = lane >> 4;
  const int gate = l15 >> 2, jj = l15 & 3;

  __shared__ __align__(16) short hs[2 * 16512];  // double-buffered 16 x 1032

  // wh slice: wave w's 16 gate-cols = packed rows (8cg+w)*16 + l15, K=1024.
  const unsigned short* wrow = whp + (size_t)((8 * cg + w) * 16 + l15) * 1024 + hi * 8;
  bf16x8 wf[32];
  #pragma unroll
  for (int ks = 0; ks < 32; ++ks) wf[ks] = *(const bf16x8*)(wrow + ks * 32);
  // pin: compiler must keep wf in registers (cannot rematerialize past asm)
  #pragma unroll
  for (int ks = 0; ks < 32; ++ks) asm volatile("" : "+v"(wf[ks]));

  const int pc = (8 * cg + w) * 16 + l15;  // permuted xp col
  const int hcol = 32 * cg + 4 * w + jj;
  const int base = (lane & 48) | jj;       // gate-gather source
  const int srow = tid >> 5;               // stage row (0..15)
  const int scol = (tid & 31) * 32;        // stage col (dwords/h-cols)
  float cst[4] = {0.f, 0.f, 0.f, 0.f};

  float xpv[4];
  #pragma unroll
  for (int ri = 0; ri < 4; ++ri)
    xpv[ri] = bf2f(xp[(size_t)(r0 + hi * 4 + ri) * 4096 + pc]);  // t = 0

  for (int t = 0; t < 512; ++t) {
    // --- stage + poll fused: re-load until all embedded tags == t
    const unsigned int* gsrc = hb2 + (t & 1) * 65536 + (r0 + srow) * 1024 + scol;
    const unsigned tagpat = (unsigned)t << 16;
    u32x4 d0, d1, d2, d3, d4, d5, d6, d7;
    while (true) {
      asm volatile("global_load_dwordx4 %0, %1, off sc0 sc1" : "=v"(d0) : "v"(gsrc) : "memory");
      asm volatile("global_load_dwordx4 %0, %1, off sc0 sc1" : "=v"(d1) : "v"(gsrc + 4) : "memory");
      asm volatile("global_load_dwordx4 %0, %1, off sc0 sc1" : "=v"(d2) : "v"(gsrc + 8) : "memory");
      asm volatile("global_load_dwordx4 %0, %1, off sc0 sc1" : "=v"(d3) : "v"(gsrc + 12) : "memory");
      asm volatile("global_load_dwordx4 %0, %1, off sc0 sc1" : "=v"(d4) : "v"(gsrc + 16) : "memory");
      asm volatile("global_load_dwordx4 %0, %1, off sc0 sc1" : "=v"(d5) : "v"(gsrc + 20) : "memory");
      asm volatile("global_load_dwordx4 %0, %1, off sc0 sc1" : "=v"(d6) : "v"(gsrc + 24) : "memory");
      asm volatile("global_load_dwordx4 %0, %1, off sc0 sc1" : "=v"(d7) : "v"(gsrc + 28) : "memory");
      asm volatile("s_waitcnt vmcnt(0)" ::: "memory");
      __builtin_amdgcn_sched_barrier(0);
      unsigned bad = 0;
      #define CK(D) bad |= ((D.x ^ tagpat) | (D.y ^ tagpat) | (D.z ^ tagpat) | (D.w ^ tagpat)) & 0xFFFF0000u
      CK(d0); CK(d1); CK(d2); CK(d3); CK(d4); CK(d5); CK(d6); CK(d7);
      #undef CK
      if (__all(bad == 0)) break;
      __builtin_amdgcn_s_sleep(1);
    }
    // pack 32 low-halves -> 16 dwords -> 4 x ds_write_b128
    short* ld = hs + (t & 1) * 16512 + srow * 1032 + scol;
    u32x4 p0, p1, p2, p3;
    p0.x = (d0.x & 0xFFFFu) | (d0.y << 16); p0.y = (d0.z & 0xFFFFu) | (d0.w << 16);
    p0.z = (d1.x & 0xFFFFu) | (d1.y << 16); p0.w = (d1.z & 0xFFFFu) | (d1.w << 16);
    p1.x = (d2.x & 0xFFFFu) | (d2.y << 16); p1.y = (d2.z & 0xFFFFu) | (d2.w << 16);
    p1.z = (d3.x & 0xFFFFu) | (d3.y << 16); p1.w = (d3.z & 0xFFFFu) | (d3.w << 16);
    p2.x = (d4.x & 0xFFFFu) | (d4.y << 16); p2.y = (d4.z & 0xFFFFu) | (d4.w << 16);
    p2.z = (d5.x & 0xFFFFu) | (d5.y << 16); p2.w = (d5.z & 0xFFFFu) | (d5.w << 16);
    p3.x = (d6.x & 0xFFFFu) | (d6.y << 16); p3.y = (d6.z & 0xFFFFu) | (d6.w << 16);
    p3.z = (d7.x & 0xFFFFu) | (d7.y << 16); p3.w = (d7.z & 0xFFFFu) | (d7.w << 16);
    *(u32x4*)(ld) = p0;
    *(u32x4*)(ld + 8) = p1;
    *(u32x4*)(ld + 16) = p2;
    *(u32x4*)(ld + 24) = p3;
    __syncthreads();

    // --- GEMM from LDS: 32 ds_read_b128 + 32 MFMA, 4 chained accumulators
    const short* hsrow = hs + (t & 1) * 16512 + l15 * 1032 + hi * 8;
    f32x4 ac0 = {}, ac1 = {}, ac2 = {}, ac3 = {};
    #pragma unroll
    for (int ks = 0; ks < 32; ks += 4) {
      ac0 = __builtin_amdgcn_mfma_f32_16x16x32_bf16(*(const bf16x8*)(hsrow + ks * 32),       wf[ks],     ac0, 0, 0, 0);
      ac1 = __builtin_amdgcn_mfma_f32_16x16x32_bf16(*(const bf16x8*)(hsrow + (ks + 1) * 32), wf[ks + 1], ac1, 0, 0, 0);
      ac2 = __builtin_amdgcn_mfma_f32_16x16x32_bf16(*(const bf16x8*)(hsrow + (ks + 2) * 32), wf[ks + 2], ac2, 0, 0, 0);
      ac3 = __builtin_amdgcn_mfma_f32_16x16x32_bf16(*(const bf16x8*)(hsrow + (ks + 3) * 32), wf[ks + 3], ac3, 0, 0, 0);
    }
    f32x4 acc = (ac0 + ac1) + (ac2 + ac3);

    float act[4];
    #pragma unroll
    for (int ri = 0; ri < 4; ++ri) {
      float v = acc[ri] + xpv[ri];
      act[ri] = (gate == 2) ? tanh_a(v) : sigm(v);
    }
    float hv[4];
    #pragma unroll
    for (int ri = 0; ri < 4; ++ri) {
      float iv = __shfl(act[ri], base);
      float fv = __shfl(act[ri], base + 4);
      float gv = __shfl(act[ri], base + 8);
      float ov = __shfl(act[ri], base + 12);
      cst[ri] = fv * cst[ri] + iv * gv;
      hv[ri] = ov * tanh_a(cst[ri]);
    }

    if (t == 511) {
      if (gate == 0) {
        #pragma unroll
        for (int ri = 0; ri < 4; ++ri) {
          int b = r0 + hi * 4 + ri;
          out[b * 1024 + hcol] = hv[ri];
          out[65536 + b * 1024 + hcol] = cst[ri];
        }
      }
      break;
    }

    // --- prefetch next step's xp (issue early, wait at xpv assignment)
    float nx[4];
    #pragma unroll
    for (int ri = 0; ri < 4; ++ri)
      nx[ri] = bf2f(xp[(size_t)((t + 1) * 64 + r0 + hi * 4 + ri) * 4096 + pc]);

    // --- tagged h store: gate-0 lanes store their own column (4 adjacent dwords/quarter)
    if (gate == 0) {
      const unsigned ntag = (unsigned)(t + 1) << 16;
      unsigned int* hb = hb2 + ((t + 1) & 1) * 65536;
      #pragma unroll
      for (int ri = 0; ri < 4; ++ri) {
        int row = r0 + hi * 4 + ri;
        ASTORE(hb + row * 1024 + hcol, (unsigned)f2bf(hv[ri]) | ntag);
      }
    }
    #pragma unroll
    for (int ri = 0; ri < 4; ++ri) xpv[ri] = nx[ri];
  }
}

// ---------------- host ----------------

extern "C" void kernel_launch(void* const* d_in, const int* in_sizes, int n_in,
                              void* d_out, int out_size, void* d_ws, size_t ws_size,
                              hipStream_t stream) {
  const float* x = (const float*)d_in[0];
  const float* wxi = (const float*)d_in[1];
  const float* whi = (const float*)d_in[2];
  const float* wxf = (const float*)d_in[3];
  const float* whf = (const float*)d_in[4];
  const float* wxg = (const float*)d_in[5];
  const float* whg = (const float*)d_in[6];
  const float* wxo = (const float*)d_in[7];
  const float* who = (const float*)d_in[8];

  char* ws = (char*)d_ws;
  unsigned short* xb  = (unsigned short*)(ws);                    // 64 MiB (dead after k_xproj)
  unsigned short* wxt = (unsigned short*)(ws + 67108864);         // 8 MiB (dead after k_xproj)
  unsigned short* whp = (unsigned short*)(ws + 75497472);         // 8 MiB
  unsigned short* xpj = (unsigned short*)(ws + 83886080);         // 256 MiB
  float*          bx4 = (float*)(ws + 352321536);                 // 16 KiB
  // tagged h buffer reuses the dead xb region (initialized AFTER k_xproj):
  unsigned int*   hb2 = (unsigned int*)(ws);                      // 512 KiB

  k_cvt_x<<<32768, 256, 0, stream>>>(x, xb, 8388608);
  k_pack_w<<<dim3(32, 32, 8), dim3(32, 8), 0, stream>>>(wxi, wxf, wxg, wxo, whi, whf, whg, who, wxt, whp);
  k_bias<<<16, 256, 0, stream>>>((const float*)d_in[9], (const float*)d_in[10],
                                 (const float*)d_in[11], (const float*)d_in[12],
                                 (const float*)d_in[13], (const float*)d_in[14],
                                 (const float*)d_in[15], (const float*)d_in[16], bx4);
  k_xproj<<<8192, 256, 0, stream>>>(xb, wxt, bx4, xpj);
  k_init<<<256, 256, 0, stream>>>((unsigned long long*)hb2);  // after k_xproj (aliases xb)

  float* out = (float*)d_out;
  void* args[] = {(void*)&whp, (void*)&xpj, (void*)&hb2, (void*)&out};
  hipLaunchCooperativeKernel((const void*)k_lstm, dim3(128), dim3(512), args, 0, stream);
}

// Round 8
// 2325.518 us; speedup vs baseline: 1.4815x; 1.4815x over previous
//
#include <hip/hip_runtime.h>

typedef short bf16x8 __attribute__((ext_vector_type(8)));
typedef float f32x4 __attribute__((ext_vector_type(4)));
typedef unsigned long long u64x2 __attribute__((ext_vector_type(2)));

__device__ __forceinline__ unsigned short f2bf(float f) {
  unsigned u = __float_as_uint(f);
  unsigned r = (u + 0x7FFFu + ((u >> 16) & 1u)) >> 16;
  return (unsigned short)r;
}
__device__ __forceinline__ float bf2f(unsigned short s) {
  return __uint_as_float(((unsigned)s) << 16);
}
__device__ __forceinline__ float sigm(float x) {
  return __builtin_amdgcn_rcpf(1.f + __expf(-x));
}
__device__ __forceinline__ float tanh_a(float x) {
  return 1.f - 2.f * __builtin_amdgcn_rcpf(__expf(2.f * x) + 1.f);
}

__device__ __forceinline__ void gload_lds16(const void* g, void* l) {
  __builtin_amdgcn_global_load_lds(
      (const __attribute__((address_space(1))) unsigned int*)g,
      (__attribute__((address_space(3))) unsigned int*)l, 16, 0, 0);
}

#define ALOAD(p)     __hip_atomic_load((p), __ATOMIC_RELAXED, __HIP_MEMORY_SCOPE_AGENT)
#define ASTORE(p, v) __hip_atomic_store((p), (v), __ATOMIC_RELAXED, __HIP_MEMORY_SCOPE_AGENT)

// ---------------- pack kernels ----------------

__global__ void k_cvt_x(const float* __restrict__ x, unsigned short* __restrict__ xb, int n4) {
  int i = blockIdx.x * blockDim.x + threadIdx.x;
  if (i < n4) {
    float4 v = ((const float4*)x)[i];
    ushort4 o;
    o.x = f2bf(v.x); o.y = f2bf(v.y); o.z = f2bf(v.z); o.w = f2bf(v.w);
    ((ushort4*)xb)[i] = o;
  }
}

__global__ void k_pack_w(const float* __restrict__ wxi, const float* __restrict__ wxf,
                         const float* __restrict__ wxg, const float* __restrict__ wxo,
                         const float* __restrict__ whi, const float* __restrict__ whf,
                         const float* __restrict__ whg, const float* __restrict__ who,
                         unsigned short* __restrict__ wxt, unsigned short* __restrict__ whp) {
  const float* srcs[8] = {wxi, wxf, wxg, wxo, whi, whf, whg, who};
  int slab = blockIdx.z;
  const float* src = srcs[slab];
  int gate = slab & 3;
  bool is_wh = slab >= 4;
  __shared__ float tile[32][33];
  int tx = threadIdx.x, ty = threadIdx.y;
  int j0 = blockIdx.x * 32, k0 = blockIdx.y * 32;
  #pragma unroll
  for (int i = 0; i < 32; i += 8)
    tile[ty + i][tx] = src[(size_t)(k0 + ty + i) * 1024 + j0 + tx];
  __syncthreads();
  unsigned short* dst = is_wh ? whp : wxt;
  #pragma unroll
  for (int i = 0; i < 32; i += 8) {
    int j = j0 + ty + i;
    int k = k0 + tx;
    float v = tile[tx][ty + i];
    int row = is_wh ? ((j >> 2) * 16 + gate * 4 + (j & 3)) : (gate * 1024 + j);
    dst[(size_t)row * 1024 + k] = f2bf(v);
  }
}

__global__ void k_bias(const float* bxi, const float* bhi, const float* bxf, const float* bhf,
                       const float* bxg, const float* bhg, const float* bxo, const float* bho,
                       float* __restrict__ bx4) {
  int n = blockIdx.x * 256 + threadIdx.x;  // 0..4095
  int gate = n >> 10, j = n & 1023;
  const float* a = gate == 0 ? bxi : gate == 1 ? bxf : gate == 2 ? bxg : bxo;
  const float* b = gate == 0 ? bhi : gate == 1 ? bhf : gate == 2 ? bhg : bho;
  bx4[n] = a[j] + b[j];
}

// init recurrence state through the SAME coherence path k_lstm uses (agent atomics).
__global__ void k_init(unsigned short* __restrict__ hbuf, unsigned int* __restrict__ flags) {
  int i = blockIdx.x * 256 + threadIdx.x;  // 0..32767
  ASTORE((unsigned long long*)hbuf + i, 0ull);
  if (i < 256) ASTORE(flags + i, 0u);
}

// ---------------- xproj GEMM: (32768x1024) @ (1024x4096) -> bf16 [t][b][pc] ----------------
// output column order = packed-wh order: pc = (j>>2)*16 + gate*4 + (j&3)

__global__ __launch_bounds__(256) void k_xproj(
    const unsigned short* __restrict__ xb,   // [32768][1024] bf16
    const unsigned short* __restrict__ wxt,  // [4096][1024]  bf16 (B^T)
    const float* __restrict__ bx4,           // [4096]
    unsigned short* __restrict__ xp)         // [512][64][4096] bf16, permuted cols
{
  __shared__ __align__(16) short As[128 * 64];
  __shared__ __align__(16) short Bs[128 * 64];
  const int tid = threadIdx.x;
  const int bid = blockIdx.x;
  const int m0 = (bid >> 5) * 128;
  const int n0 = (bid & 31) * 128;
  const int lane = tid & 63, w = tid >> 6;
  const int l15 = lane & 15, hi = lane >> 4;
  const int mrow0 = (w >> 1) * 64, ncol0 = (w & 1) * 64;

  f32x4 acc[4][4] = {};
  const char* xbB = (const char*)xb;
  const char* wtB = (const char*)wxt;

  for (int ks = 0; ks < 16; ++ks) {
    #pragma unroll
    for (int c = 0; c < 4; ++c) {
      int d = c * 4096 + tid * 16;
      int r = d >> 7;
      int kb = (d & 127) ^ ((r & 7) << 4);
      gload_lds16(xbB + ((size_t)(m0 + r) * 2048 + ks * 128 + kb), (char*)As + d);
    }
    #pragma unroll
    for (int c = 0; c < 4; ++c) {
      int d = c * 4096 + tid * 16;
      int r = d >> 7;
      int kb = (d & 127) ^ ((r & 7) << 4);
      gload_lds16(wtB + ((size_t)(n0 + r) * 2048 + ks * 128 + kb), (char*)Bs + d);
    }
    __syncthreads();
    #pragma unroll
    for (int kk = 0; kk < 2; ++kk) {
      bf16x8 a[4], b[4];
      #pragma unroll
      for (int mt = 0; mt < 4; ++mt) {
        int r = mrow0 + mt * 16 + l15;
        int byt = r * 128 + ((kk * 64 + hi * 16) ^ ((r & 7) << 4));
        a[mt] = *(const bf16x8*)((const char*)As + byt);
      }
      #pragma unroll
      for (int nt = 0; nt < 4; ++nt) {
        int r = ncol0 + nt * 16 + l15;
        int byt = r * 128 + ((kk * 64 + hi * 16) ^ ((r & 7) << 4));
        b[nt] = *(const bf16x8*)((const char*)Bs + byt);
      }
      #pragma unroll
      for (int mt = 0; mt < 4; ++mt)
        #pragma unroll
        for (int nt = 0; nt < 4; ++nt)
          acc[mt][nt] = __builtin_amdgcn_mfma_f32_16x16x32_bf16(a[mt], b[nt], acc[mt][nt], 0, 0, 0);
    }
    __syncthreads();
  }
  float bias[4];
  int pcol[4];
  #pragma unroll
  for (int nt = 0; nt < 4; ++nt) {
    int n = n0 + ncol0 + nt * 16 + l15;
    bias[nt] = bx4[n];
    int gate = n >> 10, j = n & 1023;
    pcol[nt] = (j >> 2) * 16 + gate * 4 + (j & 3);
  }
  #pragma unroll
  for (int mt = 0; mt < 4; ++mt)
    #pragma unroll
    for (int nt = 0; nt < 4; ++nt) {
      #pragma unroll
      for (int ri = 0; ri < 4; ++ri) {
        int row = m0 + mrow0 + mt * 16 + hi * 4 + ri;       // m = b*512 + t
        int prow = (row & 511) * 64 + (row >> 9);           // -> t*64 + b
        xp[(size_t)prow * 4096 + pcol[nt]] = f2bf(acc[mt][nt][ri] + bias[nt]);
      }
    }
}

// ---------------- persistent recurrence, 4 groups x 32 blocks x 512 threads ----------------
// Group q owns batch rows [16q,16q+16). Block (q,cg) owns h-cols [32cg,32cg+32);
// wave w (0..7) owns cols [32cg+4w,+4) x 4 gates (wh FORCED register-resident, 128 VGPR).
// Per step: stage 16 h-rows (32 KB) to LDS via sc0sc1 16B loads shared by 8 waves,
// MFMA from LDS, per-wave 32-flag poll (no wave0 relay, no sleep), 2 syncs/step.

__global__ __launch_bounds__(512, 1) void k_lstm(
    const unsigned short* __restrict__ whp,  // [4096][1024] bf16 packed
    const unsigned short* __restrict__ xp,   // [512][64][4096] bf16 permuted (biases folded)
    unsigned short* __restrict__ hbuf,       // [2][64][1024] bf16
    unsigned int* __restrict__ flags,        // [>=128] (zeroed by k_init)
    float* __restrict__ out)                 // h (65536) then c (65536), fp32
{
  const int bid = blockIdx.x;
  const int q = bid >> 5;         // batch group (0..3)
  const int cg = bid & 31;        // column group (0..31)
  const int r0 = q * 16;          // first batch row
  const int tid = threadIdx.x;
  const int lane = tid & 63, w = tid >> 6;     // 8 waves
  const int l15 = lane & 15, hi = lane >> 4;
  const int gate = l15 >> 2, jj = l15 & 3;

  __shared__ __align__(16) short hs[16 * 1032];  // 16 h-rows, padded stride

  // wh slice: wave w's 16 gate-cols = packed rows (8cg+w)*16 + l15
  const unsigned short* wrow = whp + (size_t)((8 * cg + w) * 16 + l15) * 1024 + hi * 8;
  bf16x8 wf[32];
  #pragma unroll
  for (int ks = 0; ks < 32; ++ks) wf[ks] = *(const bf16x8*)(wrow + ks * 32);
  // pin: force true register residency (compiler cannot rematerialize past asm).
  // launch_bounds(512,1) gives a 512-VGPR cap -> ~200 alloc, still 8 waves/CU.
  #pragma unroll
  for (int ks = 0; ks < 32; ++ks) asm volatile("" : "+v"(wf[ks]));

  const int hcol = 32 * cg + 4 * w + jj;
  const int pc = (8 * cg + w) * 16 + l15;  // permuted xp col for this lane
  const int base = (lane & 48) | jj;       // gate-gather source
  const int pbase = lane & 48;             // h-pack gather source
  const int srow = tid >> 5;               // stage: h-row (0..15)
  const int scp = tid & 31;                // stage: chunk position (0..31)
  float cst[4] = {0.f, 0.f, 0.f, 0.f};

  float xpv[4];
  #pragma unroll
  for (int ri = 0; ri < 4; ++ri)
    xpv[ri] = bf2f(xp[(size_t)(r0 + hi * 4 + ri) * 4096 + pc]);  // t = 0

  for (int t = 0; t < 512; ++t) {
    // --- stage this group's 16 h-rows into LDS (coherent 16B bypass loads)
    {
      const char* gsrc = (const char*)(hbuf + (t & 1) * 65536 + (r0 + srow) * 1024) + scp * 16;
      u64x2 tmp[4];
      #pragma unroll
      for (int i = 0; i < 4; ++i)
        asm volatile("global_load_dwordx4 %0, %1, off sc0 sc1"
                     : "=v"(tmp[i]) : "v"(gsrc + i * 512) : "memory");
      asm volatile("s_waitcnt vmcnt(0)" ::: "memory");
      __builtin_amdgcn_sched_barrier(0);
      short* ld = hs + srow * 1032 + scp * 8;
      #pragma unroll
      for (int i = 0; i < 4; ++i)
        *(bf16x8*)(ld + i * 256) = __builtin_bit_cast(bf16x8, tmp[i]);
    }
    __syncthreads();

    // --- GEMM from LDS: 32 ds_read_b128 + 32 MFMA, 4 chained accumulators
    const short* hsrow = hs + l15 * 1032 + hi * 8;
    f32x4 ac0 = {}, ac1 = {}, ac2 = {}, ac3 = {};
    #pragma unroll
    for (int ks = 0; ks < 32; ks += 4) {
      ac0 = __builtin_amdgcn_mfma_f32_16x16x32_bf16(*(const bf16x8*)(hsrow + ks * 32),       wf[ks],     ac0, 0, 0, 0);
      ac1 = __builtin_amdgcn_mfma_f32_16x16x32_bf16(*(const bf16x8*)(hsrow + (ks + 1) * 32), wf[ks + 1], ac1, 0, 0, 0);
      ac2 = __builtin_amdgcn_mfma_f32_16x16x32_bf16(*(const bf16x8*)(hsrow + (ks + 2) * 32), wf[ks + 2], ac2, 0, 0, 0);
      ac3 = __builtin_amdgcn_mfma_f32_16x16x32_bf16(*(const bf16x8*)(hsrow + (ks + 3) * 32), wf[ks + 3], ac3, 0, 0, 0);
    }
    f32x4 acc = (ac0 + ac1) + (ac2 + ac3);

    float act[4];
    #pragma unroll
    for (int ri = 0; ri < 4; ++ri) {
      float v = acc[ri] + xpv[ri];
      act[ri] = (gate == 2) ? tanh_a(v) : sigm(v);
    }
    float hv[4];
    #pragma unroll
    for (int ri = 0; ri < 4; ++ri) {
      float iv = __shfl(act[ri], base);
      float fv = __shfl(act[ri], base + 4);
      float gv = __shfl(act[ri], base + 8);
      float ov = __shfl(act[ri], base + 12);
      cst[ri] = fv * cst[ri] + iv * gv;
      hv[ri] = ov * tanh_a(cst[ri]);
    }

    if (t == 511) {
      if (gate == 0) {
        #pragma unroll
        for (int ri = 0; ri < 4; ++ri) {
          int b = r0 + hi * 4 + ri;
          out[b * 1024 + hcol] = hv[ri];
          out[65536 + b * 1024 + hcol] = cst[ri];
        }
      }
      break;
    }

    // --- pack 4 cols -> one 8B atomic store per (hi,ri) row
    unsigned short* hn = hbuf + ((t + 1) & 1) * 65536;
    #pragma unroll
    for (int ri = 0; ri < 4; ++ri) {
      int hbv = (int)f2bf(hv[ri]);
      int c0 = __shfl(hbv, pbase + 0);
      int c1 = __shfl(hbv, pbase + 1);
      int c2 = __shfl(hbv, pbase + 2);
      int c3 = __shfl(hbv, pbase + 3);
      if (l15 == 0) {
        unsigned lo = ((unsigned)c0 & 0xFFFFu) | ((unsigned)c1 << 16);
        unsigned long long hi64 = ((unsigned)c2 & 0xFFFFu) | ((unsigned)c3 << 16);
        unsigned long long pv = (unsigned long long)lo | (hi64 << 32);
        int row = r0 + hi * 4 + ri;
        ASTORE((unsigned long long*)(hn + row * 1024 + 32 * cg + 4 * w), pv);
      }
    }

    // --- publish: syncthreads drains all waves' stores (vmcnt 0), then flag
    __syncthreads();
    if (tid == 0) ASTORE(flags + bid, (unsigned)(t + 1));

    // --- prefetch next step's xp (immutable, coalesced) under the poll shadow
    float nx[4];
    #pragma unroll
    for (int ri = 0; ri < 4; ++ri)
      nx[ri] = bf2f(xp[(size_t)((t + 1) * 64 + r0 + hi * 4 + ri) * 4096 + pc]);

    // --- wait: EVERY wave polls this group's 32 flags itself (no relay, no sleep,
    // no trailing sync: each wave proceeds to its own stage; hs is safe because
    // all MFMA reads completed before the pre-flag __syncthreads).
    {
      const unsigned int* fp = flags + q * 32 + (lane & 31);
      unsigned tgt = (unsigned)(t + 1);
      while (true) {
        unsigned f = ALOAD(fp);
        if (__all(f >= tgt)) break;
      }
    }
    #pragma unroll
    for (int ri = 0; ri < 4; ++ri) xpv[ri] = nx[ri];
  }
}

// ---------------- host ----------------

extern "C" void kernel_launch(void* const* d_in, const int* in_sizes, int n_in,
                              void* d_out, int out_size, void* d_ws, size_t ws_size,
                              hipStream_t stream) {
  const float* x = (const float*)d_in[0];
  const float* wxi = (const float*)d_in[1];
  const float* whi = (const float*)d_in[2];
  const float* wxf = (const float*)d_in[3];
  const float* whf = (const float*)d_in[4];
  const float* wxg = (const float*)d_in[5];
  const float* whg = (const float*)d_in[6];
  const float* wxo = (const float*)d_in[7];
  const float* who = (const float*)d_in[8];

  char* ws = (char*)d_ws;
  unsigned short* xb  = (unsigned short*)(ws);                    // 64 MiB
  unsigned short* wxt = (unsigned short*)(ws + 67108864);         // 8 MiB (dead after k_xproj)
  unsigned short* whp = (unsigned short*)(ws + 75497472);         // 8 MiB
  unsigned short* xpj = (unsigned short*)(ws + 83886080);         // 256 MiB
  float*          bx4 = (float*)(ws + 352321536);                 // 16 KiB
  // recurrence state in its own region (never touched by normal-path writes):
  unsigned short* hbuf  = (unsigned short*)(ws + 352337920);      // 256 KiB
  unsigned int*   flags = (unsigned int*)(ws + 352337920 + 262144); // 1 KiB

  k_cvt_x<<<32768, 256, 0, stream>>>(x, xb, 8388608);
  k_pack_w<<<dim3(32, 32, 8), dim3(32, 8), 0, stream>>>(wxi, wxf, wxg, wxo, whi, whf, whg, who, wxt, whp);
  k_bias<<<16, 256, 0, stream>>>((const float*)d_in[9], (const float*)d_in[10],
                                 (const float*)d_in[11], (const float*)d_in[12],
                                 (const float*)d_in[13], (const float*)d_in[14],
                                 (const float*)d_in[15], (const float*)d_in[16], bx4);
  k_init<<<128, 256, 0, stream>>>(hbuf, flags);
  k_xproj<<<8192, 256, 0, stream>>>(xb, wxt, bx4, xpj);

  float* out = (float*)d_out;
  void* args[] = {(void*)&whp, (void*)&xpj, (void*)&hbuf, (void*)&flags, (void*)&out};
  hipLaunchCooperativeKernel((const void*)k_lstm, dim3(128), dim3(512), args, 0, stream);
}